// Round 3
// baseline (3000.340 us; speedup 1.0000x reference)
//
#include <hip/hip_runtime.h>

#define B_ 16
#define N_ 4096
#define S_ 1024
#define K_ 32
#define NSLOT 128
#define CNT_F 524288.0f   // B*S*K

// ---------------------------------------------------------------- FPS
// One block per batch. Distances in registers; xyz mirrored in LDS so the
// winning centroid is read by broadcast. Arithmetic matches np/jnp:
// ((dx*dx + dy*dy) + dz*dz), rn, no FMA contraction; first-index tie-break.
#define FPS_T 512
#define FPS_P (N_ / FPS_T)

__global__ __launch_bounds__(FPS_T) void fps_kernel(
    const float* __restrict__ xyz, int* __restrict__ fps_idx,
    float* __restrict__ out_newxyz) {
  __shared__ float xyz_s[N_ * 3];
  __shared__ float s_wv[FPS_T / 64];
  __shared__ int s_wi[FPS_T / 64];
  __shared__ int s_fi;
  int b = blockIdx.x, t = threadIdx.x;
  const float* xb = xyz + (size_t)b * N_ * 3;
  for (int i = t; i < N_ * 3; i += FPS_T) xyz_s[i] = xb[i];
  if (t == 0) s_fi = 0;
  __syncthreads();
  float px[FPS_P], py[FPS_P], pz[FPS_P], dd[FPS_P];
#pragma unroll
  for (int j = 0; j < FPS_P; ++j) {
    int n = t + j * FPS_T;
    px[j] = xyz_s[n * 3 + 0];
    py[j] = xyz_s[n * 3 + 1];
    pz[j] = xyz_s[n * 3 + 2];
    dd[j] = 1e10f;
  }
#pragma unroll 1
  for (int s = 0; s < S_; ++s) {
    int fi = s_fi;
    float cx = xyz_s[fi * 3 + 0], cy = xyz_s[fi * 3 + 1], cz = xyz_s[fi * 3 + 2];
    if (t == 0) {
      fps_idx[b * S_ + s] = fi;
      out_newxyz[((size_t)b * S_ + s) * 3 + 0] = cx;
      out_newxyz[((size_t)b * S_ + s) * 3 + 1] = cy;
      out_newxyz[((size_t)b * S_ + s) * 3 + 2] = cz;
    }
    float bv = -1.0f;
    int bi = 0;
#pragma unroll
    for (int j = 0; j < FPS_P; ++j) {
      float dx = __fsub_rn(px[j], cx);
      float dy = __fsub_rn(py[j], cy);
      float dz = __fsub_rn(pz[j], cz);
      float d = __fadd_rn(__fadd_rn(__fmul_rn(dx, dx), __fmul_rn(dy, dy)),
                          __fmul_rn(dz, dz));
      d = fminf(dd[j], d);
      dd[j] = d;
      if (d > bv) { bv = d; bi = t + j * FPS_T; }  // ascending n within lane
    }
#pragma unroll
    for (int off = 32; off > 0; off >>= 1) {
      float ov = __shfl_down(bv, off);
      int oi = __shfl_down(bi, off);
      if (ov > bv || (ov == bv && oi < bi)) { bv = ov; bi = oi; }
    }
    if ((t & 63) == 0) { s_wv[t >> 6] = bv; s_wi[t >> 6] = bi; }
    __syncthreads();
    if (t == 0) {
      float gv = s_wv[0];
      int gi = s_wi[0];
#pragma unroll
      for (int i2 = 1; i2 < FPS_T / 64; ++i2) {
        float v = s_wv[i2];
        int ii = s_wi[i2];
        if (v > gv || (v == gv && ii < gi)) { gv = v; gi = ii; }
      }
      s_fi = gi;
    }
    __syncthreads();
  }
}

// ---------------------------------------------------------------- point norms
__global__ void ptnorm_kernel(const float* __restrict__ xyz, float* __restrict__ pt) {
  int i = blockIdx.x * 256 + threadIdx.x;  // < B*N
  float x = xyz[(size_t)i * 3 + 0];
  float y = xyz[(size_t)i * 3 + 1];
  float z = xyz[(size_t)i * 3 + 2];
  pt[i] = __fadd_rn(__fadd_rn(__fmul_rn(x, x), __fmul_rn(y, y)), __fmul_rn(z, z));
}

// ---------------------------------------------------------------- kNN (K=32)
// One wave per (b,s). 32 passes of wave-argmin, lowest-index tie-break ==
// stable top_k set. Distances via the reference's norm expansion, matched rn.
__global__ __launch_bounds__(64) void knn_kernel(
    const float* __restrict__ xyz, const float* __restrict__ ptnorm,
    const float* __restrict__ newxyz, const int* __restrict__ fps_idx,
    int* __restrict__ nn_idx) {
  int bs = blockIdx.x;
  int b = bs >> 10;  // S=1024
  int lane = threadIdx.x;
  float sx = newxyz[(size_t)bs * 3 + 0];
  float sy = newxyz[(size_t)bs * 3 + 1];
  float sz = newxyz[(size_t)bs * 3 + 2];
  int fi = fps_idx[bs];
  float nxn = ptnorm[(size_t)b * N_ + fi];  // identical to ref's sum(src^2)
  const float* xb = xyz + (size_t)b * N_ * 3;
  const float* pnb = ptnorm + (size_t)b * N_;
  unsigned u[64];
#pragma unroll
  for (int j = 0; j < 64; ++j) {
    int n = j * 64 + lane;
    float x = xb[n * 3 + 0], y = xb[n * 3 + 1], z = xb[n * 3 + 2];
    float e = __fadd_rn(__fadd_rn(__fmul_rn(sx, x), __fmul_rn(sy, y)),
                        __fmul_rn(sz, z));
    float d = __fadd_rn(__fadd_rn(nxn, pnb[n]), __fmul_rn(-2.0f, e));
    int sb = __float_as_int(d);
    u[j] = (sb < 0) ? ~((unsigned)sb) : (((unsigned)sb) | 0x80000000u);
  }
  unsigned keep = 0;
#pragma unroll 1
  for (int p = 0; p < K_; ++p) {
    unsigned bv = 0xFFFFFFFFu;
    int bj = 0;
#pragma unroll
    for (int j = 0; j < 64; ++j) {
      if (u[j] < bv) { bv = u[j]; bj = j; }
    }
    unsigned bn = (unsigned)(bj * 64 + lane);
#pragma unroll
    for (int off = 32; off > 0; off >>= 1) {
      unsigned ov = __shfl_down(bv, off);
      unsigned on = __shfl_down(bn, off);
      if (ov < bv || (ov == bv && on < bn)) { bv = ov; bn = on; }
    }
    unsigned gn = __shfl(bn, 0);
    if (lane == p) keep = gn;
    if ((gn & 63u) == (unsigned)lane) {
      int gj = gn >> 6;
#pragma unroll
      for (int j = 0; j < 64; ++j)
        if (j == gj) u[j] = 0xFFFFFFFFu;
    }
  }
  if (lane < K_) nn_idx[(size_t)bs * K_ + lane] = (int)keep;
}

// ---------------------------------------------------------------- weight transpose
__global__ void prep_wT(const float* __restrict__ w0, const float* __restrict__ w1,
                        const float* __restrict__ w2, float* __restrict__ wT0,
                        float* __restrict__ wT1, float* __restrict__ wT2) {
  int t = blockIdx.x * 256 + threadIdx.x;
  if (t < 64 * 67) { int o = t / 67, c = t % 67; wT0[c * 64 + o] = w0[t]; }
  if (t < 64 * 64) { int o = t >> 6, c = t & 63; wT1[c * 64 + o] = w1[t]; }
  if (t < 128 * 64) { int o = t >> 6, c = t & 63; wT2[c * 128 + o] = w2[t]; }
}

// ---------------------------------------------------------------- stats helper
__device__ __forceinline__ void stats_accum(float acc[8][8], const float* __restrict__ bias_,
                                            int obase, int o0, int mq,
                                            float* __restrict__ stp) {
#pragma unroll
  for (int j = 0; j < 8; ++j) {
    float bv = bias_[obase + o0 + j];
    float s = 0.0f, q = 0.0f;
#pragma unroll
    for (int i = 0; i < 8; ++i) {
      float ya = acc[i][j] + bv;
      s += ya;
      q = fmaf(ya, ya, q);
    }
#pragma unroll
    for (int off = 1; off < 8; off <<= 1) {
      s += __shfl_xor(s, off);
      q += __shfl_xor(q, off);
    }
    if (mq == 0) {
      atomicAdd(&stp[(size_t)(obase + o0 + j) * 2 + 0], s);
      atomicAdd(&stp[(size_t)(obase + o0 + j) * 2 + 1], q);
    }
  }
}

// ---------------------------------------------------------------- fused layers
// One wave per 64 rows (= 2 s values x K=32). Gather feat into LDS (transposed
// [c][m]); chain GEMM0 -> bn0/relu -> GEMM1 -> bn1/relu -> GEMM2 through the
// SAME LDS buffer. PHASE 0: stats0 only. PHASE 1: +GEMM1, stats1. PHASE 2:
// full chain, stats2 + per-(s,o) max/min of raw y2 (pooling commutes with the
// BN affine). All math fp32.
template <int PHASE>
__global__ __launch_bounds__(64) void fused_layers(
    const float* __restrict__ xyz, const float* __restrict__ points,
    const float* __restrict__ newxyz, const int* __restrict__ nn_idx,
    const float* __restrict__ wT0, const float* __restrict__ bias0,
    const float* __restrict__ wT1, const float* __restrict__ bias1,
    const float* __restrict__ wT2, const float* __restrict__ bias2,
    const float* __restrict__ bnp,  // sc0@0 sh0@64 sc1@128 sh1@192
    float* __restrict__ stats, float* __restrict__ maxY, float* __restrict__ minY) {
  constexpr int MP = 68;
  __shared__ __align__(16) float xs[67 * MP];
  __shared__ int nn_s[64];
  __shared__ float nx_s[6];
  int t = threadIdx.x;
  int blk = blockIdx.x;
  int row0 = blk * 64;
  int b = blk >> 9;
  int s0 = (blk & 511) * 2;
  int bs0 = b * S_ + s0;
  nn_s[t] = nn_idx[row0 + t];
  if (t < 6) nx_s[t] = newxyz[(size_t)bs0 * 3 + t];
  __syncthreads();
  const float* xb = xyz + (size_t)b * N_ * 3;
  const float* pb = points + (size_t)b * N_ * 64;
#pragma unroll 4
  for (int m = 0; m < 64; ++m) {
    int idx = nn_s[m];
    if (t < 3) {
      xs[t * MP + m] = __fsub_rn(xb[idx * 3 + t], nx_s[(m >> 5) * 3 + t]);
      xs[(64 + t) * MP + m] = pb[(size_t)idx * 64 + 61 + t];
    } else {
      xs[t * MP + m] = pb[(size_t)idx * 64 + (t - 3)];
    }
  }
  __syncthreads();
  int mq = t & 7, oq = t >> 3;
  int m0 = mq * 8, o0 = oq * 8;
  float acc[8][8];
#pragma unroll
  for (int i = 0; i < 8; ++i)
#pragma unroll
    for (int j = 0; j < 8; ++j) acc[i][j] = 0.0f;
  // ---- GEMM0: [64 rows x 67 cin] x [67 x 64] ----
  for (int c = 0; c < 67; ++c) {
    float4 xa = *reinterpret_cast<const float4*>(&xs[c * MP + m0]);
    float4 xb4 = *reinterpret_cast<const float4*>(&xs[c * MP + m0 + 4]);
    float4 wa = *reinterpret_cast<const float4*>(&wT0[c * 64 + o0]);
    float4 wb = *reinterpret_cast<const float4*>(&wT0[c * 64 + o0 + 4]);
    float xr[8] = {xa.x, xa.y, xa.z, xa.w, xb4.x, xb4.y, xb4.z, xb4.w};
    float wr[8] = {wa.x, wa.y, wa.z, wa.w, wb.x, wb.y, wb.z, wb.w};
#pragma unroll
    for (int i = 0; i < 8; ++i)
#pragma unroll
      for (int j = 0; j < 8; ++j) acc[i][j] = fmaf(xr[i], wr[j], acc[i][j]);
  }
  if constexpr (PHASE == 0) {
    stats_accum(acc, bias0, 0, o0, mq, stats + (size_t)(blk & (NSLOT - 1)) * 64 * 2);
    return;
  } else {
    // x1 = relu(bn0(y0)) -> xs
    __syncthreads();  // all GEMM0 reads done
#pragma unroll
    for (int j = 0; j < 8; ++j) {
      float bv = bias0[o0 + j];
      float sc = bnp[o0 + j], sh = bnp[64 + o0 + j];
#pragma unroll
      for (int i = 0; i < 8; ++i) {
        float ya = acc[i][j] + bv;
        xs[(o0 + j) * MP + (m0 + i)] = fmaxf(fmaf(ya, sc, sh), 0.0f);
      }
    }
    __syncthreads();
    // ---- GEMM1: 64x64x64 ----
#pragma unroll
    for (int i = 0; i < 8; ++i)
#pragma unroll
      for (int j = 0; j < 8; ++j) acc[i][j] = 0.0f;
    for (int c = 0; c < 64; ++c) {
      float4 xa = *reinterpret_cast<const float4*>(&xs[c * MP + m0]);
      float4 xb4 = *reinterpret_cast<const float4*>(&xs[c * MP + m0 + 4]);
      float4 wa = *reinterpret_cast<const float4*>(&wT1[c * 64 + o0]);
      float4 wb = *reinterpret_cast<const float4*>(&wT1[c * 64 + o0 + 4]);
      float xr[8] = {xa.x, xa.y, xa.z, xa.w, xb4.x, xb4.y, xb4.z, xb4.w};
      float wr[8] = {wa.x, wa.y, wa.z, wa.w, wb.x, wb.y, wb.z, wb.w};
#pragma unroll
      for (int i = 0; i < 8; ++i)
#pragma unroll
        for (int j = 0; j < 8; ++j) acc[i][j] = fmaf(xr[i], wr[j], acc[i][j]);
    }
    if constexpr (PHASE == 1) {
      stats_accum(acc, bias1, 0, o0, mq, stats + (size_t)(blk & (NSLOT - 1)) * 64 * 2);
      return;
    } else {
      // x2 = relu(bn1(y1)) -> xs
      __syncthreads();
#pragma unroll
      for (int j = 0; j < 8; ++j) {
        float bv = bias1[o0 + j];
        float sc = bnp[128 + o0 + j], sh = bnp[192 + o0 + j];
#pragma unroll
        for (int i = 0; i < 8; ++i) {
          float ya = acc[i][j] + bv;
          xs[(o0 + j) * MP + (m0 + i)] = fmaxf(fmaf(ya, sc, sh), 0.0f);
        }
      }
      __syncthreads();
      // ---- GEMM2: 64x64x128, two o-halves ----
      float* stp = stats + (size_t)(blk & (NSLOT - 1)) * 128 * 2;
#pragma unroll 1
      for (int h = 0; h < 2; ++h) {
#pragma unroll
        for (int i = 0; i < 8; ++i)
#pragma unroll
          for (int j = 0; j < 8; ++j) acc[i][j] = 0.0f;
        for (int c = 0; c < 64; ++c) {
          float4 xa = *reinterpret_cast<const float4*>(&xs[c * MP + m0]);
          float4 xb4 = *reinterpret_cast<const float4*>(&xs[c * MP + m0 + 4]);
          float4 wa = *reinterpret_cast<const float4*>(&wT2[c * 128 + h * 64 + o0]);
          float4 wb = *reinterpret_cast<const float4*>(&wT2[c * 128 + h * 64 + o0 + 4]);
          float xr[8] = {xa.x, xa.y, xa.z, xa.w, xb4.x, xb4.y, xb4.z, xb4.w};
          float wr[8] = {wa.x, wa.y, wa.z, wa.w, wb.x, wb.y, wb.z, wb.w};
#pragma unroll
          for (int i = 0; i < 8; ++i)
#pragma unroll
            for (int j = 0; j < 8; ++j) acc[i][j] = fmaf(xr[i], wr[j], acc[i][j]);
        }
        stats_accum(acc, bias2, h * 64, o0, mq, stp);
        // per-(s,o) max/min of raw y2 over k (rows within this block)
#pragma unroll
        for (int j = 0; j < 8; ++j) {
          float bv = bias2[h * 64 + o0 + j];
          float mx = -3.4e38f, mn = 3.4e38f;
#pragma unroll
          for (int i = 0; i < 8; ++i) {
            float ya = acc[i][j] + bv;
            mx = fmaxf(mx, ya);
            mn = fminf(mn, ya);
          }
          mx = fmaxf(mx, __shfl_xor(mx, 1));
          mn = fminf(mn, __shfl_xor(mn, 1));
          mx = fmaxf(mx, __shfl_xor(mx, 2));
          mn = fminf(mn, __shfl_xor(mn, 2));
          if ((mq & 3) == 0) {
            size_t g = ((size_t)(bs0 + (mq >> 2))) * 128 + h * 64 + o0 + j;
            maxY[g] = mx;
            minY[g] = mn;
          }
        }
      }
    }
  }
}

// ---------------------------------------------------------------- BN finalize
__global__ void bn_finalize(const float* __restrict__ st, int cout,
                            const float* __restrict__ gamma,
                            const float* __restrict__ beta,
                            float* __restrict__ scale, float* __restrict__ shift) {
  int o = threadIdx.x;
  if (o >= cout) return;
  float s = 0.0f, q = 0.0f;
  for (int i = 0; i < NSLOT; ++i) {
    s += st[((size_t)i * cout + o) * 2 + 0];
    q += st[((size_t)i * cout + o) * 2 + 1];
  }
  float mean = s * (1.0f / CNT_F);
  float var = q * (1.0f / CNT_F) - mean * mean;
  float sc = gamma[o] / sqrtf(var + 1e-5f);
  scale[o] = sc;
  shift[o] = beta[o] - mean * sc;
}

// ---------------------------------------------------------------- pooling
// out[b,o,s] = relu(sc2*pick + sh2), pick = maxY if sc2>=0 else minY.
__global__ __launch_bounds__(256) void pool_kernel(
    const float* __restrict__ maxY, const float* __restrict__ minY,
    const float* __restrict__ bnp, float* __restrict__ out) {
  __shared__ float tile[128 * 65];
  int b = blockIdx.x >> 4;
  int sbase = (blockIdx.x & 15) * 64;
  int t = threadIdx.x;
#pragma unroll 4
  for (int i = 0; i < 32; ++i) {
    int e = i * 256 + t;  // 0..8191
    int sl = e >> 7, o = e & 127;
    float sc = bnp[256 + o], sh = bnp[384 + o];
    size_t g = ((size_t)(b * S_ + sbase + sl)) * 128 + o;
    float v = (sc >= 0.0f) ? maxY[g] : minY[g];
    tile[o * 65 + sl] = fmaxf(fmaf(v, sc, sh), 0.0f);
  }
  __syncthreads();
  int sl = t & 63;
  for (int o2 = t >> 6; o2 < 128; o2 += 4) {
    out[((size_t)(b * 128 + o2)) * S_ + sbase + sl] = tile[o2 * 65 + sl];
  }
}

// ---------------------------------------------------------------- launch
static inline size_t alup(size_t x) { return (x + 255) & ~(size_t)255; }

extern "C" void kernel_launch(void* const* d_in, const int* in_sizes, int n_in,
                              void* d_out, int out_size, void* d_ws, size_t ws_size,
                              hipStream_t stream) {
  (void)in_sizes; (void)n_in; (void)out_size;
  const float* xyz = (const float*)d_in[0];
  const float* points = (const float*)d_in[1];
  const float* w0 = (const float*)d_in[2];
  const float* b0 = (const float*)d_in[3];
  const float* g0 = (const float*)d_in[4];
  const float* be0 = (const float*)d_in[5];
  const float* w1 = (const float*)d_in[6];
  const float* b1 = (const float*)d_in[7];
  const float* g1 = (const float*)d_in[8];
  const float* be1 = (const float*)d_in[9];
  const float* w2 = (const float*)d_in[10];
  const float* b2 = (const float*)d_in[11];
  const float* g2 = (const float*)d_in[12];
  const float* be2 = (const float*)d_in[13];
  float* out_newxyz = (float*)d_out;
  float* out_newpts = out_newxyz + (size_t)B_ * S_ * 3;

  char* p = (char*)d_ws;
  int* fps = (int*)p;     p += alup((size_t)B_ * S_ * 4);
  int* nn = (int*)p;      p += alup((size_t)B_ * S_ * K_ * 4);
  float* ptn = (float*)p; p += alup((size_t)B_ * N_ * 4);
  float* st0 = (float*)p; p += (size_t)NSLOT * 64 * 2 * 4;
  float* st1 = (float*)p; p += (size_t)NSLOT * 64 * 2 * 4;
  float* st2 = (float*)p; p += (size_t)NSLOT * 128 * 2 * 4;
  float* bnp = (float*)p; p += alup(512 * 4);
  float* wT0 = (float*)p; p += alup(67 * 64 * 4);
  float* wT1 = (float*)p; p += alup(64 * 64 * 4);
  float* wT2 = (float*)p; p += alup(64 * 128 * 4);
  float* maxY = (float*)p; p += (size_t)B_ * S_ * 128 * 4;
  float* minY = (float*)p; p += (size_t)B_ * S_ * 128 * 4;
  if ((size_t)(p - (char*)d_ws) > ws_size) return;  // visible failure if ws too small

  float* sc0 = bnp;       float* sh0 = bnp + 64;
  float* sc1 = bnp + 128; float* sh1 = bnp + 192;
  float* sc2 = bnp + 256; float* sh2 = bnp + 384;

  hipMemsetAsync(st0, 0, (size_t)NSLOT * (64 + 64 + 128) * 2 * 4, stream);
  prep_wT<<<32, 256, 0, stream>>>(w0, w1, w2, wT0, wT1, wT2);
  ptnorm_kernel<<<(B_ * N_) / 256, 256, 0, stream>>>(xyz, ptn);
  fps_kernel<<<B_, FPS_T, 0, stream>>>(xyz, fps, out_newxyz);
  knn_kernel<<<B_ * S_, 64, 0, stream>>>(xyz, ptn, out_newxyz, fps, nn);
  fused_layers<0><<<(B_ * S_) / 2, 64, 0, stream>>>(
      xyz, points, out_newxyz, nn, wT0, b0, wT1, b1, wT2, b2, bnp, st0, maxY, minY);
  bn_finalize<<<1, 128, 0, stream>>>(st0, 64, g0, be0, sc0, sh0);
  fused_layers<1><<<(B_ * S_) / 2, 64, 0, stream>>>(
      xyz, points, out_newxyz, nn, wT0, b0, wT1, b1, wT2, b2, bnp, st1, maxY, minY);
  bn_finalize<<<1, 128, 0, stream>>>(st1, 64, g1, be1, sc1, sh1);
  fused_layers<2><<<(B_ * S_) / 2, 64, 0, stream>>>(
      xyz, points, out_newxyz, nn, wT0, b0, wT1, b1, wT2, b2, bnp, st2, maxY, minY);
  bn_finalize<<<1, 128, 0, stream>>>(st2, 128, g2, be2, sc2, sh2);
  pool_kernel<<<B_ * (S_ / 64), 256, 0, stream>>>(maxY, minY, bnp, out_newpts);
}

// Round 4
// 2502.567 us; speedup vs baseline: 1.1989x; 1.1989x over previous
//
#include <hip/hip_runtime.h>

#define B_ 16
#define N_ 4096
#define S_ 1024
#define K_ 32
#define NSLOT 128
#define CNT_F 524288.0f   // B*S*K

// ---------------------------------------------------------------- FPS
// One block per batch. Distances in registers; xyz mirrored in LDS so the
// winning centroid is read by broadcast. Arithmetic matches np/jnp:
// ((dx*dx + dy*dy) + dz*dz), rn, no FMA contraction; first-index tie-break.
// One barrier per iteration: wave shfl-reduce -> 8 LDS u64 atomicMax into a
// per-iteration slot -> barrier -> all threads read winner. No global stores
// inside the loop (results staged in LDS, written once at the end).
#define FPS_T 512
#define FPS_P (N_ / FPS_T)

__global__ __launch_bounds__(FPS_T) void fps_kernel(
    const float* __restrict__ xyz, int* __restrict__ fps_idx,
    float* __restrict__ out_newxyz) {
  __shared__ float xyz_s[N_ * 3];                 // 48 KB
  __shared__ unsigned long long best[S_];         // 8 KB, one slot per iter
  __shared__ int idx_s[S_];                       // 4 KB
  int b = blockIdx.x, t = threadIdx.x;
  const float* xb = xyz + (size_t)b * N_ * 3;
  for (int i = t; i < N_ * 3; i += FPS_T) xyz_s[i] = xb[i];
  for (int i = t; i < S_; i += FPS_T) best[i] = 0ULL;
  __syncthreads();
  float px[FPS_P], py[FPS_P], pz[FPS_P], dd[FPS_P];
#pragma unroll
  for (int j = 0; j < FPS_P; ++j) {
    int n = t + j * FPS_T;
    px[j] = xyz_s[n * 3 + 0];
    py[j] = xyz_s[n * 3 + 1];
    pz[j] = xyz_s[n * 3 + 2];
    dd[j] = 1e10f;
  }
  int fi = 0;
#pragma unroll 1
  for (int s = 0; s < S_; ++s) {
    if (t == 0) idx_s[s] = fi;
    float cx = xyz_s[fi * 3 + 0], cy = xyz_s[fi * 3 + 1], cz = xyz_s[fi * 3 + 2];
    float bv = -1.0f;
    int bi = 0;
#pragma unroll
    for (int j = 0; j < FPS_P; ++j) {
      float dx = __fsub_rn(px[j], cx);
      float dy = __fsub_rn(py[j], cy);
      float dz = __fsub_rn(pz[j], cz);
      float d = __fadd_rn(__fadd_rn(__fmul_rn(dx, dx), __fmul_rn(dy, dy)),
                          __fmul_rn(dz, dz));
      d = fminf(dd[j], d);
      dd[j] = d;
      if (d > bv) { bv = d; bi = t + j * FPS_T; }  // ascending n within lane
    }
#pragma unroll
    for (int off = 32; off > 0; off >>= 1) {
      float ov = __shfl_down(bv, off);
      int oi = __shfl_down(bi, off);
      if (ov > bv || (ov == bv && oi < bi)) { bv = ov; bi = oi; }
    }
    if ((t & 63) == 0) {
      // dist >= 0 so float bits are monotone; min-index tie-break via 4095-bi
      unsigned long long key =
          ((unsigned long long)__float_as_uint(bv) << 32) |
          (unsigned)(N_ - 1 - bi);
      atomicMax(&best[s], key);
    }
    __syncthreads();
    fi = (N_ - 1) - (int)(unsigned)(best[s] & 0xFFFFFFFFULL);
  }
  __syncthreads();
  for (int s = t; s < S_; s += FPS_T) {
    int i = idx_s[s];
    fps_idx[b * S_ + s] = i;
    out_newxyz[((size_t)b * S_ + s) * 3 + 0] = xyz_s[i * 3 + 0];
    out_newxyz[((size_t)b * S_ + s) * 3 + 1] = xyz_s[i * 3 + 1];
    out_newxyz[((size_t)b * S_ + s) * 3 + 2] = xyz_s[i * 3 + 2];
  }
}

// ---------------------------------------------------------------- point norms
__global__ void ptnorm_kernel(const float* __restrict__ xyz, float* __restrict__ pt) {
  int i = blockIdx.x * 256 + threadIdx.x;  // < B*N
  float x = xyz[(size_t)i * 3 + 0];
  float y = xyz[(size_t)i * 3 + 1];
  float z = xyz[(size_t)i * 3 + 2];
  pt[i] = __fadd_rn(__fadd_rn(__fmul_rn(x, x), __fmul_rn(y, y)), __fmul_rn(z, z));
}

// ---------------------------------------------------------------- kNN (K=32)
// One wave per (b,s). 32 passes of wave-argmin, lowest-index tie-break ==
// stable top_k set. Distances via the reference's norm expansion, matched rn.
__global__ __launch_bounds__(64) void knn_kernel(
    const float* __restrict__ xyz, const float* __restrict__ ptnorm,
    const float* __restrict__ newxyz, const int* __restrict__ fps_idx,
    int* __restrict__ nn_idx) {
  int bs = blockIdx.x;
  int b = bs >> 10;  // S=1024
  int lane = threadIdx.x;
  float sx = newxyz[(size_t)bs * 3 + 0];
  float sy = newxyz[(size_t)bs * 3 + 1];
  float sz = newxyz[(size_t)bs * 3 + 2];
  int fi = fps_idx[bs];
  float nxn = ptnorm[(size_t)b * N_ + fi];  // identical to ref's sum(src^2)
  const float* xb = xyz + (size_t)b * N_ * 3;
  const float* pnb = ptnorm + (size_t)b * N_;
  unsigned u[64];
#pragma unroll
  for (int j = 0; j < 64; ++j) {
    int n = j * 64 + lane;
    float x = xb[n * 3 + 0], y = xb[n * 3 + 1], z = xb[n * 3 + 2];
    float e = __fadd_rn(__fadd_rn(__fmul_rn(sx, x), __fmul_rn(sy, y)),
                        __fmul_rn(sz, z));
    float d = __fadd_rn(__fadd_rn(nxn, pnb[n]), __fmul_rn(-2.0f, e));
    int sb = __float_as_int(d);
    u[j] = (sb < 0) ? ~((unsigned)sb) : (((unsigned)sb) | 0x80000000u);
  }
  unsigned keep = 0;
#pragma unroll 1
  for (int p = 0; p < K_; ++p) {
    unsigned bv = 0xFFFFFFFFu;
    int bj = 0;
#pragma unroll
    for (int j = 0; j < 64; ++j) {
      if (u[j] < bv) { bv = u[j]; bj = j; }
    }
    unsigned bn = (unsigned)(bj * 64 + lane);
#pragma unroll
    for (int off = 32; off > 0; off >>= 1) {
      unsigned ov = __shfl_down(bv, off);
      unsigned on = __shfl_down(bn, off);
      if (ov < bv || (ov == bv && on < bn)) { bv = ov; bn = on; }
    }
    unsigned gn = __shfl(bn, 0);
    if (lane == p) keep = gn;
    if ((gn & 63u) == (unsigned)lane) {
      int gj = gn >> 6;
#pragma unroll
      for (int j = 0; j < 64; ++j)
        if (j == gj) u[j] = 0xFFFFFFFFu;
    }
  }
  if (lane < K_) nn_idx[(size_t)bs * K_ + lane] = (int)keep;
}

// ---------------------------------------------------------------- weight transpose
__global__ void prep_wT(const float* __restrict__ w0, const float* __restrict__ w1,
                        const float* __restrict__ w2, float* __restrict__ wT0,
                        float* __restrict__ wT1, float* __restrict__ wT2) {
  int t = blockIdx.x * 256 + threadIdx.x;
  if (t < 64 * 67) { int o = t / 67, c = t % 67; wT0[c * 64 + o] = w0[t]; }
  if (t < 64 * 64) { int o = t >> 6, c = t & 63; wT1[c * 64 + o] = w1[t]; }
  if (t < 128 * 64) { int o = t >> 6, c = t & 63; wT2[c * 128 + o] = w2[t]; }
}

// ---------------------------------------------------------------- stats helper
__device__ __forceinline__ void stats_accum(float acc[8][8], const float* __restrict__ bias_,
                                            int obase, int o0, int mq,
                                            float* __restrict__ stp) {
#pragma unroll
  for (int j = 0; j < 8; ++j) {
    float bv = bias_[obase + o0 + j];
    float s = 0.0f, q = 0.0f;
#pragma unroll
    for (int i = 0; i < 8; ++i) {
      float ya = acc[i][j] + bv;
      s += ya;
      q = fmaf(ya, ya, q);
    }
#pragma unroll
    for (int off = 1; off < 8; off <<= 1) {
      s += __shfl_xor(s, off);
      q += __shfl_xor(q, off);
    }
    if (mq == 0) {
      atomicAdd(&stp[(size_t)(obase + o0 + j) * 2 + 0], s);
      atomicAdd(&stp[(size_t)(obase + o0 + j) * 2 + 1], q);
    }
  }
}

// ---------------------------------------------------------------- fused layers
// One wave per 64 rows (= 2 s values x K=32). Gather feat into LDS (transposed
// [c][m]); chain GEMM0 -> bn0/relu -> GEMM1 -> bn1/relu -> GEMM2 through the
// SAME LDS buffer. PHASE 0: stats0 only. PHASE 1: +GEMM1, stats1. PHASE 2:
// full chain, stats2 + per-(s,o) max/min of raw y2 (pooling commutes with the
// BN affine). All math fp32.
template <int PHASE>
__global__ __launch_bounds__(64) void fused_layers(
    const float* __restrict__ xyz, const float* __restrict__ points,
    const float* __restrict__ newxyz, const int* __restrict__ nn_idx,
    const float* __restrict__ wT0, const float* __restrict__ bias0,
    const float* __restrict__ wT1, const float* __restrict__ bias1,
    const float* __restrict__ wT2, const float* __restrict__ bias2,
    const float* __restrict__ bnp,  // sc0@0 sh0@64 sc1@128 sh1@192
    float* __restrict__ stats, float* __restrict__ maxY, float* __restrict__ minY) {
  constexpr int MP = 68;
  __shared__ __align__(16) float xs[67 * MP];
  __shared__ int nn_s[64];
  __shared__ float nx_s[6];
  int t = threadIdx.x;
  int blk = blockIdx.x;
  int row0 = blk * 64;
  int b = blk >> 9;
  int s0 = (blk & 511) * 2;
  int bs0 = b * S_ + s0;
  nn_s[t] = nn_idx[row0 + t];
  if (t < 6) nx_s[t] = newxyz[(size_t)bs0 * 3 + t];
  __syncthreads();
  const float* xb = xyz + (size_t)b * N_ * 3;
  const float* pb = points + (size_t)b * N_ * 64;
#pragma unroll 4
  for (int m = 0; m < 64; ++m) {
    int idx = nn_s[m];
    if (t < 3) {
      xs[t * MP + m] = __fsub_rn(xb[idx * 3 + t], nx_s[(m >> 5) * 3 + t]);
      xs[(64 + t) * MP + m] = pb[(size_t)idx * 64 + 61 + t];
    } else {
      xs[t * MP + m] = pb[(size_t)idx * 64 + (t - 3)];
    }
  }
  __syncthreads();
  int mq = t & 7, oq = t >> 3;
  int m0 = mq * 8, o0 = oq * 8;
  float acc[8][8];
#pragma unroll
  for (int i = 0; i < 8; ++i)
#pragma unroll
    for (int j = 0; j < 8; ++j) acc[i][j] = 0.0f;
  // ---- GEMM0: [64 rows x 67 cin] x [67 x 64] ----
#pragma unroll 2
  for (int c = 0; c < 67; ++c) {
    float4 xa = *reinterpret_cast<const float4*>(&xs[c * MP + m0]);
    float4 xb4 = *reinterpret_cast<const float4*>(&xs[c * MP + m0 + 4]);
    float4 wa = *reinterpret_cast<const float4*>(&wT0[c * 64 + o0]);
    float4 wb = *reinterpret_cast<const float4*>(&wT0[c * 64 + o0 + 4]);
    float xr[8] = {xa.x, xa.y, xa.z, xa.w, xb4.x, xb4.y, xb4.z, xb4.w};
    float wr[8] = {wa.x, wa.y, wa.z, wa.w, wb.x, wb.y, wb.z, wb.w};
#pragma unroll
    for (int i = 0; i < 8; ++i)
#pragma unroll
      for (int j = 0; j < 8; ++j) acc[i][j] = fmaf(xr[i], wr[j], acc[i][j]);
  }
  if constexpr (PHASE == 0) {
    stats_accum(acc, bias0, 0, o0, mq, stats + (size_t)(blk & (NSLOT - 1)) * 64 * 2);
    return;
  } else {
    // x1 = relu(bn0(y0)) -> xs
    __syncthreads();  // all GEMM0 reads done
#pragma unroll
    for (int j = 0; j < 8; ++j) {
      float bv = bias0[o0 + j];
      float sc = bnp[o0 + j], sh = bnp[64 + o0 + j];
#pragma unroll
      for (int i = 0; i < 8; ++i) {
        float ya = acc[i][j] + bv;
        xs[(o0 + j) * MP + (m0 + i)] = fmaxf(fmaf(ya, sc, sh), 0.0f);
      }
    }
    __syncthreads();
    // ---- GEMM1: 64x64x64 ----
#pragma unroll
    for (int i = 0; i < 8; ++i)
#pragma unroll
      for (int j = 0; j < 8; ++j) acc[i][j] = 0.0f;
#pragma unroll 2
    for (int c = 0; c < 64; ++c) {
      float4 xa = *reinterpret_cast<const float4*>(&xs[c * MP + m0]);
      float4 xb4 = *reinterpret_cast<const float4*>(&xs[c * MP + m0 + 4]);
      float4 wa = *reinterpret_cast<const float4*>(&wT1[c * 64 + o0]);
      float4 wb = *reinterpret_cast<const float4*>(&wT1[c * 64 + o0 + 4]);
      float xr[8] = {xa.x, xa.y, xa.z, xa.w, xb4.x, xb4.y, xb4.z, xb4.w};
      float wr[8] = {wa.x, wa.y, wa.z, wa.w, wb.x, wb.y, wb.z, wb.w};
#pragma unroll
      for (int i = 0; i < 8; ++i)
#pragma unroll
        for (int j = 0; j < 8; ++j) acc[i][j] = fmaf(xr[i], wr[j], acc[i][j]);
    }
    if constexpr (PHASE == 1) {
      stats_accum(acc, bias1, 0, o0, mq, stats + (size_t)(blk & (NSLOT - 1)) * 64 * 2);
      return;
    } else {
      // x2 = relu(bn1(y1)) -> xs
      __syncthreads();
#pragma unroll
      for (int j = 0; j < 8; ++j) {
        float bv = bias1[o0 + j];
        float sc = bnp[128 + o0 + j], sh = bnp[192 + o0 + j];
#pragma unroll
        for (int i = 0; i < 8; ++i) {
          float ya = acc[i][j] + bv;
          xs[(o0 + j) * MP + (m0 + i)] = fmaxf(fmaf(ya, sc, sh), 0.0f);
        }
      }
      __syncthreads();
      // ---- GEMM2: 64x64x128, two o-halves ----
      float* stp = stats + (size_t)(blk & (NSLOT - 1)) * 128 * 2;
#pragma unroll 1
      for (int h = 0; h < 2; ++h) {
#pragma unroll
        for (int i = 0; i < 8; ++i)
#pragma unroll
          for (int j = 0; j < 8; ++j) acc[i][j] = 0.0f;
#pragma unroll 2
        for (int c = 0; c < 64; ++c) {
          float4 xa = *reinterpret_cast<const float4*>(&xs[c * MP + m0]);
          float4 xb4 = *reinterpret_cast<const float4*>(&xs[c * MP + m0 + 4]);
          float4 wa = *reinterpret_cast<const float4*>(&wT2[c * 128 + h * 64 + o0]);
          float4 wb = *reinterpret_cast<const float4*>(&wT2[c * 128 + h * 64 + o0 + 4]);
          float xr[8] = {xa.x, xa.y, xa.z, xa.w, xb4.x, xb4.y, xb4.z, xb4.w};
          float wr[8] = {wa.x, wa.y, wa.z, wa.w, wb.x, wb.y, wb.z, wb.w};
#pragma unroll
          for (int i = 0; i < 8; ++i)
#pragma unroll
            for (int j = 0; j < 8; ++j) acc[i][j] = fmaf(xr[i], wr[j], acc[i][j]);
        }
        stats_accum(acc, bias2, h * 64, o0, mq, stp);
        // per-(s,o) max/min of raw y2 over k (rows within this block)
#pragma unroll
        for (int j = 0; j < 8; ++j) {
          float bv = bias2[h * 64 + o0 + j];
          float mx = -3.4e38f, mn = 3.4e38f;
#pragma unroll
          for (int i = 0; i < 8; ++i) {
            float ya = acc[i][j] + bv;
            mx = fmaxf(mx, ya);
            mn = fminf(mn, ya);
          }
          mx = fmaxf(mx, __shfl_xor(mx, 1));
          mn = fminf(mn, __shfl_xor(mn, 1));
          mx = fmaxf(mx, __shfl_xor(mx, 2));
          mn = fminf(mn, __shfl_xor(mn, 2));
          if ((mq & 3) == 0) {
            size_t g = ((size_t)(bs0 + (mq >> 2))) * 128 + h * 64 + o0 + j;
            maxY[g] = mx;
            minY[g] = mn;
          }
        }
      }
    }
  }
}

// ---------------------------------------------------------------- BN finalize
__global__ void bn_finalize(const float* __restrict__ st, int cout,
                            const float* __restrict__ gamma,
                            const float* __restrict__ beta,
                            float* __restrict__ scale, float* __restrict__ shift) {
  int o = threadIdx.x;
  if (o >= cout) return;
  float s = 0.0f, q = 0.0f;
  for (int i = 0; i < NSLOT; ++i) {
    s += st[((size_t)i * cout + o) * 2 + 0];
    q += st[((size_t)i * cout + o) * 2 + 1];
  }
  float mean = s * (1.0f / CNT_F);
  float var = q * (1.0f / CNT_F) - mean * mean;
  float sc = gamma[o] / sqrtf(var + 1e-5f);
  scale[o] = sc;
  shift[o] = beta[o] - mean * sc;
}

// ---------------------------------------------------------------- pooling
// out[b,o,s] = relu(sc2*pick + sh2), pick = maxY if sc2>=0 else minY.
__global__ __launch_bounds__(256) void pool_kernel(
    const float* __restrict__ maxY, const float* __restrict__ minY,
    const float* __restrict__ bnp, float* __restrict__ out) {
  __shared__ float tile[128 * 65];
  int b = blockIdx.x >> 4;
  int sbase = (blockIdx.x & 15) * 64;
  int t = threadIdx.x;
#pragma unroll 4
  for (int i = 0; i < 32; ++i) {
    int e = i * 256 + t;  // 0..8191
    int sl = e >> 7, o = e & 127;
    float sc = bnp[256 + o], sh = bnp[384 + o];
    size_t g = ((size_t)(b * S_ + sbase + sl)) * 128 + o;
    float v = (sc >= 0.0f) ? maxY[g] : minY[g];
    tile[o * 65 + sl] = fmaxf(fmaf(v, sc, sh), 0.0f);
  }
  __syncthreads();
  int sl = t & 63;
  for (int o2 = t >> 6; o2 < 128; o2 += 4) {
    out[((size_t)(b * 128 + o2)) * S_ + sbase + sl] = tile[o2 * 65 + sl];
  }
}

// ---------------------------------------------------------------- launch
static inline size_t alup(size_t x) { return (x + 255) & ~(size_t)255; }

extern "C" void kernel_launch(void* const* d_in, const int* in_sizes, int n_in,
                              void* d_out, int out_size, void* d_ws, size_t ws_size,
                              hipStream_t stream) {
  (void)in_sizes; (void)n_in; (void)out_size;
  const float* xyz = (const float*)d_in[0];
  const float* points = (const float*)d_in[1];
  const float* w0 = (const float*)d_in[2];
  const float* b0 = (const float*)d_in[3];
  const float* g0 = (const float*)d_in[4];
  const float* be0 = (const float*)d_in[5];
  const float* w1 = (const float*)d_in[6];
  const float* b1 = (const float*)d_in[7];
  const float* g1 = (const float*)d_in[8];
  const float* be1 = (const float*)d_in[9];
  const float* w2 = (const float*)d_in[10];
  const float* b2 = (const float*)d_in[11];
  const float* g2 = (const float*)d_in[12];
  const float* be2 = (const float*)d_in[13];
  float* out_newxyz = (float*)d_out;
  float* out_newpts = out_newxyz + (size_t)B_ * S_ * 3;

  char* p = (char*)d_ws;
  int* fps = (int*)p;     p += alup((size_t)B_ * S_ * 4);
  int* nn = (int*)p;      p += alup((size_t)B_ * S_ * K_ * 4);
  float* ptn = (float*)p; p += alup((size_t)B_ * N_ * 4);
  float* st0 = (float*)p; p += (size_t)NSLOT * 64 * 2 * 4;
  float* st1 = (float*)p; p += (size_t)NSLOT * 64 * 2 * 4;
  float* st2 = (float*)p; p += (size_t)NSLOT * 128 * 2 * 4;
  float* bnp = (float*)p; p += alup(512 * 4);
  float* wT0 = (float*)p; p += alup(67 * 64 * 4);
  float* wT1 = (float*)p; p += alup(64 * 64 * 4);
  float* wT2 = (float*)p; p += alup(64 * 128 * 4);
  float* maxY = (float*)p; p += (size_t)B_ * S_ * 128 * 4;
  float* minY = (float*)p; p += (size_t)B_ * S_ * 128 * 4;
  if ((size_t)(p - (char*)d_ws) > ws_size) return;  // visible failure if ws too small

  float* sc0 = bnp;       float* sh0 = bnp + 64;
  float* sc1 = bnp + 128; float* sh1 = bnp + 192;
  float* sc2 = bnp + 256; float* sh2 = bnp + 384;

  hipMemsetAsync(st0, 0, (size_t)NSLOT * (64 + 64 + 128) * 2 * 4, stream);
  prep_wT<<<32, 256, 0, stream>>>(w0, w1, w2, wT0, wT1, wT2);
  ptnorm_kernel<<<(B_ * N_) / 256, 256, 0, stream>>>(xyz, ptn);
  fps_kernel<<<B_, FPS_T, 0, stream>>>(xyz, fps, out_newxyz);
  knn_kernel<<<B_ * S_, 64, 0, stream>>>(xyz, ptn, out_newxyz, fps, nn);
  fused_layers<0><<<(B_ * S_) / 2, 64, 0, stream>>>(
      xyz, points, out_newxyz, nn, wT0, b0, wT1, b1, wT2, b2, bnp, st0, maxY, minY);
  bn_finalize<<<1, 128, 0, stream>>>(st0, 64, g0, be0, sc0, sh0);
  fused_layers<1><<<(B_ * S_) / 2, 64, 0, stream>>>(
      xyz, points, out_newxyz, nn, wT0, b0, wT1, b1, wT2, b2, bnp, st1, maxY, minY);
  bn_finalize<<<1, 128, 0, stream>>>(st1, 64, g1, be1, sc1, sh1);
  fused_layers<2><<<(B_ * S_) / 2, 64, 0, stream>>>(
      xyz, points, out_newxyz, nn, wT0, b0, wT1, b1, wT2, b2, bnp, st2, maxY, minY);
  bn_finalize<<<1, 128, 0, stream>>>(st2, 128, g2, be2, sc2, sh2);
  pool_kernel<<<B_ * (S_ / 64), 256, 0, stream>>>(maxY, minY, bnp, out_newpts);
}